// Round 1
// baseline (1730.386 us; speedup 1.0000x reference)
//
#include <hip/hip_runtime.h>
#include <hip/hip_bf16.h>

#define EPS 1e-5f
#define SLOPE 0.01f

// ---------------------------------------------------------------------------
// Gather-GEMM-scatter: acc[dst[k,e], :64] += x[src[k,e], :CIN] @ W[k]  (atomic)
// grid = (GX, 27), block = 256 (4 waves). W[k] staged in LDS; each wave
// processes 4 edges per iteration with x rows in wave-local LDS.
// ---------------------------------------------------------------------------
template<int CIN>
__global__ __launch_bounds__(256) void conv_scatter(
    const float* __restrict__ x, const float* __restrict__ W,
    const int* __restrict__ src, const int* __restrict__ dst,
    float* __restrict__ acc, int E)
{
    __shared__ float Wl[CIN * 64];
    __shared__ float xl[4][4 * CIN];   // per-wave: 4 edges x CIN
    const int k   = blockIdx.y;
    const int tid = threadIdx.x;
    const int w   = tid >> 6;          // wave id 0..3
    const int c   = tid & 63;          // lane = output channel

    const float* Wk = W + (size_t)k * (CIN * 64);
    for (int i = tid * 4; i < CIN * 64; i += 256 * 4)
        *(float4*)&Wl[i] = *(const float4*)&Wk[i];
    __syncthreads();

    const int* srcK = src + (size_t)k * E;
    const int* dstK = dst + (size_t)k * E;
    float* xw = xl[w];

    for (int e0 = blockIdx.x * 16 + w * 4; e0 < E; e0 += gridDim.x * 16) {
        const int ne = min(4, E - e0);
        for (int j = 0; j < ne; ++j) {
            const int s = srcK[e0 + j];
            #pragma unroll
            for (int h = 0; h < CIN / 64; ++h)
                xw[j * CIN + h * 64 + c] = x[(size_t)s * CIN + h * 64 + c];
        }
        __builtin_amdgcn_wave_barrier();

        float a0 = 0.f, a1 = 0.f, a2 = 0.f, a3 = 0.f;
        #pragma unroll 4
        for (int i = 0; i < CIN; i += 4) {
            const float4 x0 = *(const float4*)&xw[0 * CIN + i];
            const float4 x1 = *(const float4*)&xw[1 * CIN + i];
            const float4 x2 = *(const float4*)&xw[2 * CIN + i];
            const float4 x3 = *(const float4*)&xw[3 * CIN + i];
            const float w0 = Wl[(i + 0) * 64 + c];
            const float w1 = Wl[(i + 1) * 64 + c];
            const float w2 = Wl[(i + 2) * 64 + c];
            const float w3 = Wl[(i + 3) * 64 + c];
            a0 = fmaf(x0.w, w3, fmaf(x0.z, w2, fmaf(x0.y, w1, fmaf(x0.x, w0, a0))));
            a1 = fmaf(x1.w, w3, fmaf(x1.z, w2, fmaf(x1.y, w1, fmaf(x1.x, w0, a1))));
            a2 = fmaf(x2.w, w3, fmaf(x2.z, w2, fmaf(x2.y, w1, fmaf(x2.x, w0, a2))));
            a3 = fmaf(x3.w, w3, fmaf(x3.z, w2, fmaf(x3.y, w1, fmaf(x3.x, w0, a3))));
        }
        __builtin_amdgcn_wave_barrier();

        if (ne > 0) { const int d = dstK[e0 + 0]; atomicAdd(&acc[(size_t)d * 64 + c], a0); }
        if (ne > 1) { const int d = dstK[e0 + 1]; atomicAdd(&acc[(size_t)d * 64 + c], a1); }
        if (ne > 2) { const int d = dstK[e0 + 2]; atomicAdd(&acc[(size_t)d * 64 + c], a2); }
        if (ne > 3) { const int d = dstK[e0 + 3]; atomicAdd(&acc[(size_t)d * 64 + c], a3); }
    }
}

// ---------------------------------------------------------------------------
// Cout=1 conv: acc1[dst] += dot(s[src,:64], W_sum[k,:,0]). Thread-per-edge.
// ---------------------------------------------------------------------------
__global__ __launch_bounds__(256) void conv_sum_kernel(
    const float* __restrict__ s, const float* __restrict__ Wsum,
    const int* __restrict__ src, const int* __restrict__ dst,
    float* __restrict__ acc1, int E)
{
    const int k = blockIdx.y;
    __shared__ float Wl[64];
    if (threadIdx.x < 64) Wl[threadIdx.x] = Wsum[k * 64 + threadIdx.x];
    __syncthreads();
    for (int e = blockIdx.x * 256 + threadIdx.x; e < E; e += gridDim.x * 256) {
        const int si = src[(size_t)k * E + e];
        const float4* row = (const float4*)(s + (size_t)si * 64);
        float acc = 0.f;
        #pragma unroll
        for (int q = 0; q < 16; ++q) {
            const float4 v = row[q];
            acc = fmaf(v.x, Wl[q * 4 + 0], acc);
            acc = fmaf(v.y, Wl[q * 4 + 1], acc);
            acc = fmaf(v.z, Wl[q * 4 + 2], acc);
            acc = fmaf(v.w, Wl[q * 4 + 3], acc);
        }
        atomicAdd(&acc1[dst[(size_t)k * E + e]], acc);
    }
}

// ---------------------------------------------------------------------------
// Cin=1 conv: out[dst,:64] += s1[src] * W_up[k,0,:]. Wave-per-edge.
// gsrc = gather indices (coarse), sdst = scatter indices (fine).
// ---------------------------------------------------------------------------
__global__ __launch_bounds__(256) void conv_up_kernel(
    const float* __restrict__ s1, const float* __restrict__ Wup,
    const int* __restrict__ gsrc, const int* __restrict__ sdst,
    float* __restrict__ out, int E)
{
    const int k = blockIdx.y;
    const int c = threadIdx.x & 63;
    const int w = threadIdx.x >> 6;
    const float wv = Wup[k * 64 + c];
    for (int e = blockIdx.x * 4 + w; e < E; e += gridDim.x * 4) {
        const float val = s1[gsrc[(size_t)k * E + e]];
        const int   di  = sdst[(size_t)k * E + e];
        atomicAdd(&out[(size_t)di * 64 + c], val * wv);
    }
}

// ---------------------------------------------------------------------------
// Per-channel (C=64) sum/sumsq over N rows -> st[0:64]=sum, st[64:128]=sumsq
// ---------------------------------------------------------------------------
__global__ __launch_bounds__(256) void stats64(
    const float* __restrict__ x, int N, float* __restrict__ st)
{
    const int c  = threadIdx.x & 63;
    const int rg = threadIdx.x >> 6;
    float s = 0.f, q = 0.f;
    for (int r = blockIdx.x * 4 + rg; r < N; r += gridDim.x * 4) {
        const float v = x[(size_t)r * 64 + c];
        s += v;
        q = fmaf(v, v, q);
    }
    __shared__ float ls[256], lq[256];
    ls[threadIdx.x] = s; lq[threadIdx.x] = q;
    __syncthreads();
    if (threadIdx.x < 64) {
        s = ls[c] + ls[64 + c] + ls[128 + c] + ls[192 + c];
        q = lq[c] + lq[64 + c] + lq[128 + c] + lq[192 + c];
        atomicAdd(&st[c], s);
        atomicAdd(&st[64 + c], q);
    }
}

// Single-channel stats: st[0]=sum, st[1]=sumsq
__global__ __launch_bounds__(256) void stats1(
    const float* __restrict__ x, int N, float* __restrict__ st)
{
    float s = 0.f, q = 0.f;
    for (int i = blockIdx.x * 256 + threadIdx.x; i < N; i += gridDim.x * 256) {
        const float v = x[i];
        s += v;
        q = fmaf(v, v, q);
    }
    __shared__ float ls[256], lq[256];
    ls[threadIdx.x] = s; lq[threadIdx.x] = q;
    __syncthreads();
    for (int off = 128; off > 0; off >>= 1) {
        if (threadIdx.x < off) {
            ls[threadIdx.x] += ls[threadIdx.x + off];
            lq[threadIdx.x] += lq[threadIdx.x + off];
        }
        __syncthreads();
    }
    if (threadIdx.x == 0) { atomicAdd(&st[0], ls[0]); atomicAdd(&st[1], lq[0]); }
}

// ---------------------------------------------------------------------------
// In-place BN + activation (ACT 0=LeakyReLU, 1=sigmoid), optional += add.
// Bias-before-BN is exactly BN-invariant, so biases are skipped upstream.
// ---------------------------------------------------------------------------
template<int ACT>
__global__ __launch_bounds__(256) void apply_bn(
    float* __restrict__ x, const float* __restrict__ st, int N, float invN,
    const float* __restrict__ gam, const float* __restrict__ bet,
    const float* __restrict__ add)
{
    __shared__ float sc[64], sh[64];
    if (threadIdx.x < 64) {
        const int c = threadIdx.x;
        const float m = st[c] * invN;
        const float v = st[64 + c] * invN - m * m;
        const float s = rsqrtf(v + EPS) * gam[c];
        sc[c] = s;
        sh[c] = bet[c] - m * s;
    }
    __syncthreads();
    const size_t n = (size_t)N * 64;
    for (size_t i = (size_t)blockIdx.x * 256 + threadIdx.x; i < n;
         i += (size_t)gridDim.x * 256) {
        const int c = (int)(i & 63);
        float y = fmaf(x[i], sc[c], sh[c]);
        if (ACT == 0) y = (y >= 0.f) ? y : SLOPE * y;
        else          y = 1.f / (1.f + __expf(-y));
        if (add) y += add[i];
        x[i] = y;
    }
}

__global__ __launch_bounds__(256) void apply_bn1(
    float* __restrict__ x, const float* __restrict__ st, int N, float invN,
    const float* __restrict__ gam, const float* __restrict__ bet)
{
    const float m  = st[0] * invN;
    const float v  = st[1] * invN - m * m;
    const float s  = rsqrtf(v + EPS) * gam[0];
    const float sh = bet[0] - m * s;
    for (int i = blockIdx.x * 256 + threadIdx.x; i < N; i += gridDim.x * 256) {
        const float y = fmaf(x[i], s, sh);
        x[i] = (y >= 0.f) ? y : SLOPE * y;
    }
}

// ---------------------------------------------------------------------------
extern "C" void kernel_launch(void* const* d_in, const int* in_sizes, int n_in,
                              void* d_out, int out_size, void* d_ws, size_t ws_size,
                              hipStream_t stream)
{
    const float* gate     = (const float*)d_in[0];
    const float* shortcut = (const float*)d_in[1];
    const int*   src_down = (const int*)d_in[2];
    const int*   dst_down = (const int*)d_in[3];
    const int*   src_g    = (const int*)d_in[4];
    const int*   dst_g    = (const int*)d_in[5];
    const float* W_sc     = (const float*)d_in[6];
    const float* W_g      = (const float*)d_in[8];
    const float* W_gu     = (const float*)d_in[10];
    const float* W_sum    = (const float*)d_in[12];
    const float* W_up     = (const float*)d_in[13];
    const float* gam_sc   = (const float*)d_in[15];
    const float* bet_sc   = (const float*)d_in[16];
    const float* gam_g    = (const float*)d_in[17];
    const float* bet_g    = (const float*)d_in[18];
    const float* gam_gu   = (const float*)d_in[19];
    const float* bet_gu   = (const float*)d_in[20];
    const float* gam_sum  = (const float*)d_in[21];
    const float* bet_sum  = (const float*)d_in[22];
    const float* gam_up   = (const float*)d_in[23];
    const float* bet_up   = (const float*)d_in[24];

    const int K   = 27;
    const int Nc  = in_sizes[0] / 128;   // 60000
    const int Nf  = in_sizes[1] / 64;    // 200000
    const int Ekd = in_sizes[2] / K;     // 40000
    const int Ekg = in_sizes[4] / K;     // 25000

    float* A  = (float*)d_ws;            // acc_theta -> theta
    float* B  = A + (size_t)Nc * 64;     // acc_phi   -> phi
    float* C  = B + (size_t)Nc * 64;     // acc_phi2  -> s
    float* D  = C + (size_t)Nc * 64;     // acc_s1    -> s1
    float* ST = D + Nc;                  // stats: 640 floats
    const size_t zeroBytes = ((size_t)Nc * 64 * 3 + (size_t)Nc + 640) * sizeof(float);
    hipMemsetAsync(d_ws, 0, zeroBytes, stream);
    hipMemsetAsync(d_out, 0, (size_t)out_size * sizeof(float), stream);
    float* out = (float*)d_out;

    const dim3 blk(256);

    // theta = leaky(bn(sconv(shortcut, W_sc, src_down->dst_down)))
    conv_scatter<64><<<dim3(64, K), blk, 0, stream>>>(shortcut, W_sc, src_down, dst_down, A, Ekd);
    // phi_raw = sconv(gate, W_g, src_g->dst_g)
    conv_scatter<128><<<dim3(64, K), blk, 0, stream>>>(gate, W_g, src_g, dst_g, B, Ekg);

    stats64<<<256, blk, 0, stream>>>(A, Nc, ST + 0);
    stats64<<<256, blk, 0, stream>>>(B, Nc, ST + 128);
    apply_bn<0><<<1024, blk, 0, stream>>>(A, ST + 0,   Nc, 1.0f / Nc, gam_sc, bet_sc, nullptr);
    apply_bn<0><<<1024, blk, 0, stream>>>(B, ST + 128, Nc, 1.0f / Nc, gam_g,  bet_g,  nullptr);

    // phi = leaky(bn(sconv(phi, W_gu, dst_g->src_g)))  (transposed index pairs)
    conv_scatter<64><<<dim3(64, K), blk, 0, stream>>>(B, W_gu, dst_g, src_g, C, Ekg);
    stats64<<<256, blk, 0, stream>>>(C, Nc, ST + 256);
    // s = leaky(bn(C)) + theta
    apply_bn<0><<<1024, blk, 0, stream>>>(C, ST + 256, Nc, 1.0f / Nc, gam_gu, bet_gu, A);

    // s1 = leaky(bn(sconv(s, W_sum, src_g->dst_g)))   (Cout = 1)
    conv_sum_kernel<<<dim3(32, K), blk, 0, stream>>>(C, W_sum, src_g, dst_g, D, Ekg);
    stats1<<<256, blk, 0, stream>>>(D, Nc, ST + 384);
    apply_bn1<<<256, blk, 0, stream>>>(D, ST + 384, Nc, 1.0f / Nc, gam_sum, bet_sum);

    // out = sigmoid(bn(sconv(s1, W_up, dst_down->src_down)))  (Cin = 1, fine res)
    conv_up_kernel<<<dim3(64, K), blk, 0, stream>>>(D, W_up, dst_down, src_down, out, Ekd);
    stats64<<<512, blk, 0, stream>>>(out, Nf, ST + 512);
    apply_bn<1><<<2048, blk, 0, stream>>>(out, ST + 512, Nf, 1.0f / Nf, gam_up, bet_up, nullptr);
}